// Round 1
// baseline (5396.084 us; speedup 1.0000x reference)
//
#include <hip/hip_runtime.h>

#define B_DIM   2
#define S_TOT   10548
#define M_ROWS  (B_DIM * S_TOT)   // 21096
#define E_DIM   256
#define NH_DIM  8
#define HD_DIM  32
#define DF_DIM  1024
#define NLAYERS 6

// ---------------------------------------------------------------------------
// Input assembly: x[b,s,e] = feat_lvl[b,e,j];  pos[b,s,e] = pos_lvl[b,e,j] + lemb[lvl,e]
// ---------------------------------------------------------------------------
__global__ __launch_bounds__(256)
void assemble_kernel(const float* __restrict__ f0, const float* __restrict__ p0,
                     const float* __restrict__ f1, const float* __restrict__ p1,
                     const float* __restrict__ f2, const float* __restrict__ p2,
                     const float* __restrict__ f3, const float* __restrict__ p3,
                     const float* __restrict__ lemb,
                     float* __restrict__ x, float* __restrict__ pos)
{
    int idx = blockIdx.x * 256 + threadIdx.x;   // over M_ROWS*E
    int e = idx & (E_DIM - 1);
    int r = idx >> 8;
    int b = r / S_TOT;
    int s = r - b * S_TOT;
    const float* f; const float* p; int lvl, j, n;
    if (s < 9216)       { lvl = 0; j = s;         n = 9216; f = f0; p = p0; }
    else if (s < 10368) { lvl = 1; j = s - 9216;  n = 1152; f = f1; p = p1; }
    else if (s < 10512) { lvl = 2; j = s - 10368; n = 144;  f = f2; p = p2; }
    else                { lvl = 3; j = s - 10512; n = 36;   f = f3; p = p3; }
    size_t o = (size_t)(b * E_DIM + e) * n + j;
    x[idx]   = f[o];
    pos[idx] = p[o] + lemb[lvl * E_DIM + e];
}

// ---------------------------------------------------------------------------
// fp32 tiled GEMM: C[M,N] = A[M,K] (+A2) @ B[K,N] + bias, optional relu,
// optional permuted store into value layout (B,NH,S,HD).
// 64x64 tile, K-step 16, 256 threads, each 4x4 outputs.
// ---------------------------------------------------------------------------
template<bool ADD_POS, bool RELU, bool VALPERM>
__global__ __launch_bounds__(256)
void gemm_kernel(const float* __restrict__ A, const float* __restrict__ A2,
                 const float* __restrict__ Bm, const float* __restrict__ bias,
                 float* __restrict__ C, int M, int N, int K)
{
    __shared__ float As[16][68];   // [k][m], padded
    __shared__ float Bs[16][68];   // [k][n], padded
    int t  = threadIdx.x;
    int tx = t & 15, ty = t >> 4;
    int row0 = blockIdx.y * 64;
    int n0   = blockIdx.x * 64;
    float acc[4][4] = {};

    int lm   = t >> 2;          // 0..63  (m for A load)
    int lk   = (t & 3) * 4;     // 0,4,8,12 (k for A load)
    int lb_k = t >> 4;          // 0..15  (k for B load)
    int lb_n = (t & 15) * 4;    // 0..60  (n for B load)

    for (int k0 = 0; k0 < K; k0 += 16) {
        int row = row0 + lm;
        float4 av = make_float4(0.f, 0.f, 0.f, 0.f);
        if (row < M) {
            av = *reinterpret_cast<const float4*>(A + (size_t)row * K + k0 + lk);
            if (ADD_POS) {
                float4 pv = *reinterpret_cast<const float4*>(A2 + (size_t)row * K + k0 + lk);
                av.x += pv.x; av.y += pv.y; av.z += pv.z; av.w += pv.w;
            }
        }
        As[lk + 0][lm] = av.x;
        As[lk + 1][lm] = av.y;
        As[lk + 2][lm] = av.z;
        As[lk + 3][lm] = av.w;
        float4 bv = *reinterpret_cast<const float4*>(Bm + (size_t)(k0 + lb_k) * N + n0 + lb_n);
        *reinterpret_cast<float4*>(&Bs[lb_k][lb_n]) = bv;
        __syncthreads();
        #pragma unroll
        for (int kk = 0; kk < 16; ++kk) {
            float4 a4 = *reinterpret_cast<const float4*>(&As[kk][ty * 4]);
            float4 b4 = *reinterpret_cast<const float4*>(&Bs[kk][tx * 4]);
            float aa[4] = {a4.x, a4.y, a4.z, a4.w};
            float bb[4] = {b4.x, b4.y, b4.z, b4.w};
            #pragma unroll
            for (int i = 0; i < 4; ++i)
                #pragma unroll
                for (int j = 0; j < 4; ++j)
                    acc[i][j] += aa[i] * bb[j];
        }
        __syncthreads();
    }

    float bb[4];
    #pragma unroll
    for (int j = 0; j < 4; ++j) bb[j] = bias[n0 + tx * 4 + j];
    #pragma unroll
    for (int i = 0; i < 4; ++i) {
        int rr = row0 + ty * 4 + i;
        if (rr >= M) break;
        float4 o;
        o.x = acc[i][0] + bb[0];
        o.y = acc[i][1] + bb[1];
        o.z = acc[i][2] + bb[2];
        o.w = acc[i][3] + bb[3];
        if (RELU) {
            o.x = fmaxf(o.x, 0.f); o.y = fmaxf(o.y, 0.f);
            o.z = fmaxf(o.z, 0.f); o.w = fmaxf(o.w, 0.f);
        }
        if (VALPERM) {
            int b = rr / S_TOT; int s = rr - b * S_TOT;
            int c = n0 + tx * 4;            // 4-chunk never crosses a head boundary (4 | 32)
            int h = c >> 5; int hd = c & 31;
            *reinterpret_cast<float4*>(C + ((size_t)(b * NH_DIM + h) * S_TOT + s) * HD_DIM + hd) = o;
        } else {
            *reinterpret_cast<float4*>(C + (size_t)rr * N + n0 + tx * 4) = o;
        }
    }
}

// ---------------------------------------------------------------------------
// Deformable sampling: one 32-lane group per (b,s,h); lane = channel.
// Inline softmax over 16 logits; coords = ref*size + off - 0.5 (normalizer cancels).
// ---------------------------------------------------------------------------
__global__ __launch_bounds__(256)
void sample_kernel(const float* __restrict__ value,   // (B,NH,S,HD)
                   const float* __restrict__ off,     // (M,384)
                   const float* __restrict__ attn,    // (M,128) logits
                   float* __restrict__ samp)          // (M,E)
{
    int t = threadIdx.x;
    int g = blockIdx.x * 8 + (t >> 5);   // group over M*NH
    int lane = t & 31;
    int h = g & 7;
    int r = g >> 3;                       // b*S + s
    int b = r / S_TOT;
    int s = r - b * S_TOT;

    float rx, ry, rz;
    {
        int j;
        if (s < 9216)       { j = s;         int qx = j % 48; int q2 = j / 48; int qy = q2 % 48; int qz = q2 / 48;
                              rx = (qx + 0.5f) * (1.f/48); ry = (qy + 0.5f) * (1.f/48); rz = (qz + 0.5f) * (1.f/4); }
        else if (s < 10368) { j = s - 9216;  int qx = j % 24; int q2 = j / 24; int qy = q2 % 24; int qz = q2 / 24;
                              rx = (qx + 0.5f) * (1.f/24); ry = (qy + 0.5f) * (1.f/24); rz = (qz + 0.5f) * (1.f/2); }
        else if (s < 10512) { j = s - 10368; int qx = j % 12; int qy = j / 12;
                              rx = (qx + 0.5f) * (1.f/12); ry = (qy + 0.5f) * (1.f/12); rz = 0.5f; }
        else                { j = s - 10512; int qx = j % 6;  int qy = j / 6;
                              rx = (qx + 0.5f) * (1.f/6);  ry = (qy + 0.5f) * (1.f/6);  rz = 0.5f; }
    }

    const float* al = attn + (size_t)r * 128 + h * 16;
    float e[16];
    float mx = -1e30f;
    #pragma unroll
    for (int i = 0; i < 16; ++i) { e[i] = al[i]; mx = fmaxf(mx, e[i]); }
    float sum = 0.f;
    #pragma unroll
    for (int i = 0; i < 16; ++i) { e[i] = expf(e[i] - mx); sum += e[i]; }
    float inv = 1.f / sum;

    const float* ofs = off + (size_t)r * 384 + h * 48;
    float acc = 0.f;

    static constexpr int LDd[4] = {4, 2, 1, 1};
    static constexpr int LHh[4] = {48, 24, 12, 6};
    static constexpr int LWw[4] = {48, 24, 12, 6};
    static constexpr int LS0[4] = {0, 9216, 10368, 10512};

    #pragma unroll
    for (int lvl = 0; lvl < 4; ++lvl) {
        const int Dl = LDd[lvl], Hl = LHh[lvl], Wl = LWw[lvl];
        const float* vbase = value + ((size_t)(b * NH_DIM + h) * S_TOT + LS0[lvl]) * HD_DIM + lane;
        #pragma unroll
        for (int p = 0; p < 4; ++p) {
            float ox = ofs[(lvl * 4 + p) * 3 + 0];
            float oy = ofs[(lvl * 4 + p) * 3 + 1];
            float oz = ofs[(lvl * 4 + p) * 3 + 2];
            float aw = e[lvl * 4 + p] * inv;
            float cx = rx * Wl + ox - 0.5f;
            float cy = ry * Hl + oy - 0.5f;
            float cz = rz * Dl + oz - 0.5f;
            float xf = floorf(cx), yf = floorf(cy), zf = floorf(cz);
            float fx = cx - xf, fy = cy - yf, fz = cz - zf;
            int x0 = (int)xf, y0 = (int)yf, z0 = (int)zf;
            #pragma unroll
            for (int dz = 0; dz < 2; ++dz) {
                int iz = z0 + dz; float wz = dz ? fz : 1.f - fz;
                if (iz < 0 || iz >= Dl) continue;
                #pragma unroll
                for (int dy = 0; dy < 2; ++dy) {
                    int iy = y0 + dy; float wy = dy ? fy : 1.f - fy;
                    if (iy < 0 || iy >= Hl) continue;
                    #pragma unroll
                    for (int dx = 0; dx < 2; ++dx) {
                        int ix = x0 + dx; float wx = dx ? fx : 1.f - fx;
                        if (ix < 0 || ix >= Wl) continue;
                        float wgt = aw * wx * wy * wz;
                        acc += wgt * vbase[(size_t)((iz * Hl + iy) * Wl + ix) * HD_DIM];
                    }
                }
            }
        }
    }
    samp[(size_t)r * E_DIM + h * HD_DIM + lane] = acc;
}

// ---------------------------------------------------------------------------
// x = LayerNorm(x + y) * g + b   (one 256-thread block per row)
// ---------------------------------------------------------------------------
__global__ __launch_bounds__(256)
void add_ln_kernel(float* __restrict__ x, const float* __restrict__ y,
                   const float* __restrict__ g, const float* __restrict__ bta)
{
    int r = blockIdx.x;
    int t = threadIdx.x;
    size_t o = (size_t)r * E_DIM + t;
    float v = x[o] + y[o];
    float s1 = v, s2 = v * v;
    #pragma unroll
    for (int ofs = 32; ofs >= 1; ofs >>= 1) {
        s1 += __shfl_xor(s1, ofs, 64);
        s2 += __shfl_xor(s2, ofs, 64);
    }
    __shared__ float r1[4], r2[4];
    int w = t >> 6;
    if ((t & 63) == 0) { r1[w] = s1; r2[w] = s2; }
    __syncthreads();
    float S1 = r1[0] + r1[1] + r1[2] + r1[3];
    float S2 = r2[0] + r2[1] + r2[2] + r2[3];
    float mean = S1 * (1.f / E_DIM);
    float var  = S2 * (1.f / E_DIM) - mean * mean;
    x[o] = (v - mean) * rsqrtf(var + 1e-5f) * g[t] + bta[t];
}

// ---------------------------------------------------------------------------
extern "C" void kernel_launch(void* const* d_in, const int* in_sizes, int n_in,
                              void* d_out, int out_size, void* d_ws, size_t ws_size,
                              hipStream_t stream)
{
    const float* f0     = (const float*)d_in[0];
    const float* p0     = (const float*)d_in[1];
    const float* f1     = (const float*)d_in[2];
    const float* p1     = (const float*)d_in[3];
    const float* f2     = (const float*)d_in[4];
    const float* p2     = (const float*)d_in[5];
    const float* f3     = (const float*)d_in[6];
    const float* p3     = (const float*)d_in[7];
    const float* lemb   = (const float*)d_in[8];
    const float* W_off  = (const float*)d_in[9];
    const float* b_off  = (const float*)d_in[10];
    const float* W_attn = (const float*)d_in[11];
    const float* b_attn = (const float*)d_in[12];
    const float* W_val  = (const float*)d_in[13];
    const float* b_val  = (const float*)d_in[14];
    const float* W_out  = (const float*)d_in[15];
    const float* b_out  = (const float*)d_in[16];
    const float* ln1_g  = (const float*)d_in[17];
    const float* ln1_b  = (const float*)d_in[18];
    const float* W_ff1  = (const float*)d_in[19];
    const float* b_ff1  = (const float*)d_in[20];
    const float* W_ff2  = (const float*)d_in[21];
    const float* b_ff2  = (const float*)d_in[22];
    const float* ln2_g  = (const float*)d_in[23];
    const float* ln2_b  = (const float*)d_in[24];

    float* x  = (float*)d_out;                 // x lives in d_out (B,S,E) fp32
    float* ws = (float*)d_ws;
    const size_t ME = (size_t)M_ROWS * E_DIM;  // 5,400,576 floats

    float* pos    = ws;
    float* tmp    = ws + ME;
    float* region = ws + 2 * ME;               // 86.4 MB region
    float* value  = region;                                    // M*256
    float* offb   = value + ME;                                // M*384
    float* attnb  = offb + (size_t)M_ROWS * 384;               // M*128
    float* sampb  = attnb + (size_t)M_ROWS * 128;              // M*256
    float* hidden = region;  // aliases value+off+attn+samp == exactly M*1024 floats

    dim3 blk(256);
    assemble_kernel<<<(M_ROWS * E_DIM) / 256, blk, 0, stream>>>(
        f0, p0, f1, p1, f2, p2, f3, p3, lemb, x, pos);

    const int MT = (M_ROWS + 63) / 64;  // 330
    for (int l = 0; l < NLAYERS; ++l) {
        const float* Wv = W_val  + (size_t)l * E_DIM * E_DIM;
        const float* bv = b_val  + l * E_DIM;
        const float* Wo = W_off  + (size_t)l * E_DIM * 384;
        const float* bo = b_off  + l * 384;
        const float* Wa = W_attn + (size_t)l * E_DIM * 128;
        const float* ba = b_attn + l * 128;
        const float* Wp = W_out  + (size_t)l * E_DIM * E_DIM;
        const float* bp = b_out  + l * E_DIM;
        const float* W1 = W_ff1  + (size_t)l * E_DIM * DF_DIM;
        const float* b1 = b_ff1  + l * DF_DIM;
        const float* W2 = W_ff2  + (size_t)l * DF_DIM * E_DIM;
        const float* b2 = b_ff2  + l * E_DIM;

        gemm_kernel<false, false, true ><<<dim3(E_DIM / 64, MT), blk, 0, stream>>>(
            x, nullptr, Wv, bv, value, M_ROWS, E_DIM, E_DIM);
        gemm_kernel<true,  false, false><<<dim3(384 / 64, MT), blk, 0, stream>>>(
            x, pos, Wo, bo, offb, M_ROWS, 384, E_DIM);
        gemm_kernel<true,  false, false><<<dim3(128 / 64, MT), blk, 0, stream>>>(
            x, pos, Wa, ba, attnb, M_ROWS, 128, E_DIM);
        sample_kernel<<<M_ROWS, blk, 0, stream>>>(value, offb, attnb, sampb);
        gemm_kernel<false, false, false><<<dim3(E_DIM / 64, MT), blk, 0, stream>>>(
            sampb, nullptr, Wp, bp, tmp, M_ROWS, E_DIM, E_DIM);
        add_ln_kernel<<<M_ROWS, blk, 0, stream>>>(x, tmp, ln1_g + l * E_DIM, ln1_b + l * E_DIM);
        gemm_kernel<false, true,  false><<<dim3(DF_DIM / 64, MT), blk, 0, stream>>>(
            x, nullptr, W1, b1, hidden, M_ROWS, DF_DIM, E_DIM);
        gemm_kernel<false, false, false><<<dim3(E_DIM / 64, MT), blk, 0, stream>>>(
            hidden, nullptr, W2, b2, tmp, M_ROWS, E_DIM, DF_DIM);
        add_ln_kernel<<<M_ROWS, blk, 0, stream>>>(x, tmp, ln2_g + l * E_DIM, ln2_b + l * E_DIM);
    }
}

// Round 2
// 1791.826 us; speedup vs baseline: 3.0115x; 3.0115x over previous
//
#include <hip/hip_runtime.h>

#define S_TOT   10548
#define M_ROWS  21096
#define M_PAD   21120          // 165 * 128
#define E_DIM   256
#define NH_DIM  8
#define HD_DIM  32
#define DF_DIM  1024
#define NLAYERS 6

typedef unsigned short ushort_t;
typedef __attribute__((ext_vector_type(8))) short bf16x8;
typedef __attribute__((ext_vector_type(4))) float f32x4;

__device__ inline ushort_t f2bf(float f) {
    unsigned u = __float_as_uint(f);
    u += 0x7FFF + ((u >> 16) & 1);          // RNE
    return (ushort_t)(u >> 16);
}
__device__ inline float bf2f(ushort_t h) {
    return __uint_as_float(((unsigned)h) << 16);
}

// ---------------------------------------------------------------------------
// Input assembly: x fp32, pos bf16, xb = bf16(x), qb = bf16(x+pos)
// ---------------------------------------------------------------------------
__global__ __launch_bounds__(256)
void assemble_kernel(const float* __restrict__ f0, const float* __restrict__ p0,
                     const float* __restrict__ f1, const float* __restrict__ p1,
                     const float* __restrict__ f2, const float* __restrict__ p2,
                     const float* __restrict__ f3, const float* __restrict__ p3,
                     const float* __restrict__ lemb,
                     float* __restrict__ x, ushort_t* __restrict__ posb,
                     ushort_t* __restrict__ xb, ushort_t* __restrict__ qb)
{
    int idx = blockIdx.x * 256 + threadIdx.x;   // over M_ROWS*E
    int e = idx & (E_DIM - 1);
    int r = idx >> 8;
    int b = (r >= S_TOT) ? 1 : 0;
    int s = r - b * S_TOT;
    const float* f; const float* p; int lvl, j, n;
    if (s < 9216)       { lvl = 0; j = s;         n = 9216; f = f0; p = p0; }
    else if (s < 10368) { lvl = 1; j = s - 9216;  n = 1152; f = f1; p = p1; }
    else if (s < 10512) { lvl = 2; j = s - 10368; n = 144;  f = f2; p = p2; }
    else                { lvl = 3; j = s - 10512; n = 36;   f = f3; p = p3; }
    size_t o = (size_t)(b * E_DIM + e) * n + j;
    float xv = f[o];
    float pv = p[o] + lemb[lvl * E_DIM + e];
    x[idx]    = xv;
    posb[idx] = f2bf(pv);
    xb[idx]   = f2bf(xv);
    qb[idx]   = f2bf(xv + pv);
}

// ---------------------------------------------------------------------------
// Weight convert+transpose: src f32 [L,K,N] -> dst bf16 [L,N,K]
// ---------------------------------------------------------------------------
__global__ __launch_bounds__(256)
void transpose_cvt_kernel(const float* __restrict__ src, ushort_t* __restrict__ dst,
                          int K, int N)
{
    __shared__ float tile[32][33];
    int l  = blockIdx.z;
    int n0 = blockIdx.x * 32, k0 = blockIdx.y * 32;
    int tx = threadIdx.x & 31, ty = threadIdx.x >> 5;
    const float* s = src + (size_t)l * K * N;
    ushort_t* d    = dst + (size_t)l * K * N;
    #pragma unroll
    for (int i = 0; i < 32; i += 8)
        tile[ty + i][tx] = s[(size_t)(k0 + ty + i) * N + n0 + tx];
    __syncthreads();
    #pragma unroll
    for (int i = 0; i < 32; i += 8)
        d[(size_t)(n0 + ty + i) * K + k0 + tx] = f2bf(tile[tx][ty + i]);
}

// ---------------------------------------------------------------------------
// bf16 MFMA GEMM: C[M,N] = A[M,K](bf16) @ Bt[N,K](bf16)^T + bias
// 128x128 block tile, BK=32, 4 waves each 64x64 (4x4 of 16x16x32 mfma).
// OUT_MODE: 0 = fp32 [M,N], 1 = bf16 [M,N], 2 = fp32 value-permuted (B,NH,S,HD)
// ---------------------------------------------------------------------------
template<int OUT_MODE, bool RELU>
__global__ __launch_bounds__(256)
void gemm_bf16(const ushort_t* __restrict__ A, const ushort_t* __restrict__ Bt,
               const float* __restrict__ bias, float* __restrict__ Cf,
               ushort_t* __restrict__ Cb, int M, int N, int K)
{
    __shared__ short As[128 * 40];
    __shared__ short Bs[128 * 40];
    int t    = threadIdx.x;
    int row0 = blockIdx.y * 128;
    int n0   = blockIdx.x * 128;
    int lane = t & 63;
    int w    = t >> 6;
    int wm   = (w >> 1) * 64, wn = (w & 1) * 64;
    const int quad = lane >> 4, lrow = lane & 15;

    f32x4 acc[4][4];
    #pragma unroll
    for (int i = 0; i < 4; ++i)
        #pragma unroll
        for (int j = 0; j < 4; ++j)
            acc[i][j] = (f32x4){0.f, 0.f, 0.f, 0.f};

    int sr = t >> 2, sk = (t & 3) * 8;

    for (int k0 = 0; k0 < K; k0 += 32) {
        bf16x8 a0 = *(const bf16x8*)(A  + (size_t)(row0 + sr)      * K + k0 + sk);
        bf16x8 a1 = *(const bf16x8*)(A  + (size_t)(row0 + sr + 64) * K + k0 + sk);
        bf16x8 b0 = *(const bf16x8*)(Bt + (size_t)(n0 + sr)        * K + k0 + sk);
        bf16x8 b1 = *(const bf16x8*)(Bt + (size_t)(n0 + sr + 64)   * K + k0 + sk);
        __syncthreads();
        *(bf16x8*)&As[sr * 40 + sk]        = a0;
        *(bf16x8*)&As[(sr + 64) * 40 + sk] = a1;
        *(bf16x8*)&Bs[sr * 40 + sk]        = b0;
        *(bf16x8*)&Bs[(sr + 64) * 40 + sk] = b1;
        __syncthreads();

        bf16x8 af[4], bfr[4];
        #pragma unroll
        for (int i = 0; i < 4; ++i)
            af[i] = *(const bf16x8*)&As[(wm + i * 16 + lrow) * 40 + quad * 8];
        #pragma unroll
        for (int j = 0; j < 4; ++j)
            bfr[j] = *(const bf16x8*)&Bs[(wn + j * 16 + lrow) * 40 + quad * 8];
        #pragma unroll
        for (int i = 0; i < 4; ++i)
            #pragma unroll
            for (int j = 0; j < 4; ++j)
                acc[i][j] = __builtin_amdgcn_mfma_f32_16x16x32_bf16(af[i], bfr[j], acc[i][j], 0, 0, 0);
    }

    #pragma unroll
    for (int j = 0; j < 4; ++j) {
        int col = n0 + wn + j * 16 + lrow;
        float bia = bias[col];
        #pragma unroll
        for (int i = 0; i < 4; ++i) {
            #pragma unroll
            for (int rg = 0; rg < 4; ++rg) {
                int row = row0 + wm + i * 16 + quad * 4 + rg;
                if (row < M) {
                    float v = acc[i][j][rg] + bia;
                    if (RELU) v = fmaxf(v, 0.f);
                    if (OUT_MODE == 0) {
                        Cf[(size_t)row * N + col] = v;
                    } else if (OUT_MODE == 1) {
                        Cb[(size_t)row * N + col] = f2bf(v);
                    } else {
                        int b = (row >= S_TOT) ? 1 : 0;
                        int s = row - b * S_TOT;
                        int hh = col >> 5, hd = col & 31;
                        Cf[(((size_t)(b * NH_DIM + hh)) * S_TOT + s) * HD_DIM + hd] = v;
                    }
                }
            }
        }
    }
}

// ---------------------------------------------------------------------------
// Deformable sampling: 8 lanes per (b,s,h); lane owns 4 channels (float4).
// value fp32 (B,NH,S,HD); off/attn bf16; output bf16 (M,E).
// ---------------------------------------------------------------------------
__global__ __launch_bounds__(256)
void sample_kernel(const float* __restrict__ value,
                   const ushort_t* __restrict__ offb,
                   const ushort_t* __restrict__ attnb,
                   ushort_t* __restrict__ sampb)
{
    int t  = threadIdx.x;
    int g  = blockIdx.x * 32 + (t >> 3);    // group over M*NH
    int c4 = (t & 7) * 4;                   // channel base
    int h  = g & 7;
    int r  = g >> 3;
    int b  = (r >= S_TOT) ? 1 : 0;
    int s  = r - b * S_TOT;

    float rx, ry, rz;
    {
        int j;
        if (s < 9216)       { j = s;         int qx = j % 48; int q2 = j / 48; int qy = q2 % 48; int qz = q2 / 48;
                              rx = (qx + 0.5f) * (1.f/48); ry = (qy + 0.5f) * (1.f/48); rz = (qz + 0.5f) * (1.f/4); }
        else if (s < 10368) { j = s - 9216;  int qx = j % 24; int q2 = j / 24; int qy = q2 % 24; int qz = q2 / 24;
                              rx = (qx + 0.5f) * (1.f/24); ry = (qy + 0.5f) * (1.f/24); rz = (qz + 0.5f) * (1.f/2); }
        else if (s < 10512) { j = s - 10368; int qx = j % 12; int qy = j / 12;
                              rx = (qx + 0.5f) * (1.f/12); ry = (qy + 0.5f) * (1.f/12); rz = 0.5f; }
        else                { j = s - 10512; int qx = j % 6;  int qy = j / 6;
                              rx = (qx + 0.5f) * (1.f/6);  ry = (qy + 0.5f) * (1.f/6);  rz = 0.5f; }
    }

    // softmax over 16 logits (bf16)
    const ushort_t* al = attnb + (size_t)r * 128 + h * 16;
    float e[16];
    float mx = -1e30f;
    #pragma unroll
    for (int i = 0; i < 16; ++i) { e[i] = bf2f(al[i]); mx = fmaxf(mx, e[i]); }
    float sum = 0.f;
    #pragma unroll
    for (int i = 0; i < 16; ++i) { e[i] = __expf(e[i] - mx); sum += e[i]; }
    float inv = 1.f / sum;
    #pragma unroll
    for (int i = 0; i < 16; ++i) e[i] *= inv;

    // offsets (bf16)
    const ushort_t* ofs = offb + (size_t)r * 384 + h * 48;
    float o[48];
    #pragma unroll
    for (int i = 0; i < 48; ++i) o[i] = bf2f(ofs[i]);

    f32x4 acc = (f32x4){0.f, 0.f, 0.f, 0.f};

    const int LD[4] = {4, 2, 1, 1};
    const int LH[4] = {48, 24, 12, 6};
    const int LW[4] = {48, 24, 12, 6};
    const int LS0[4] = {0, 9216, 10368, 10512};

    #pragma unroll
    for (int lvl = 0; lvl < 4; ++lvl) {
        const int Dl = LD[lvl], Hl = LH[lvl], Wl = LW[lvl];
        const float* vb = value + ((size_t)(b * NH_DIM + h) * S_TOT + LS0[lvl]) * HD_DIM + c4;
        #pragma unroll
        for (int p = 0; p < 4; ++p) {
            int pi = lvl * 4 + p;
            float aw = e[pi];
            float cx = rx * Wl + o[pi * 3 + 0] - 0.5f;
            float cy = ry * Hl + o[pi * 3 + 1] - 0.5f;
            float cz = rz * Dl + o[pi * 3 + 2] - 0.5f;
            float xf = floorf(cx), yf = floorf(cy), zf = floorf(cz);
            float fx = cx - xf, fy = cy - yf, fz = cz - zf;
            int x0 = (int)xf, y0 = (int)yf, z0 = (int)zf;

            float wxa[2]; int xia[2];
            float wya[2]; int yia[2];
            float wza[2]; int zia[2];
            wxa[0] = ((unsigned)x0 < (unsigned)Wl) ? 1.f - fx : 0.f;
            wxa[1] = ((unsigned)(x0 + 1) < (unsigned)Wl) ? fx : 0.f;
            xia[0] = min(max(x0, 0), Wl - 1);
            xia[1] = min(max(x0 + 1, 0), Wl - 1);
            wya[0] = ((unsigned)y0 < (unsigned)Hl) ? 1.f - fy : 0.f;
            wya[1] = ((unsigned)(y0 + 1) < (unsigned)Hl) ? fy : 0.f;
            yia[0] = min(max(y0, 0), Hl - 1);
            yia[1] = min(max(y0 + 1, 0), Hl - 1);
            wza[0] = ((unsigned)z0 < (unsigned)Dl) ? 1.f - fz : 0.f;
            wza[1] = ((unsigned)(z0 + 1) < (unsigned)Dl) ? fz : 0.f;
            zia[0] = min(max(z0, 0), Dl - 1);
            zia[1] = min(max(z0 + 1, 0), Dl - 1);

            #pragma unroll
            for (int dz = 0; dz < 2; ++dz) {
                #pragma unroll
                for (int dy = 0; dy < 2; ++dy) {
                    float wzy = aw * wza[dz] * wya[dy];
                    const float* pz = vb + (size_t)((zia[dz] * Hl + yia[dy]) * Wl) * HD_DIM;
                    #pragma unroll
                    for (int dx = 0; dx < 2; ++dx) {
                        float wgt = wzy * wxa[dx];
                        f32x4 v = *(const f32x4*)(pz + (size_t)xia[dx] * HD_DIM);
                        acc += wgt * v;
                    }
                }
            }
        }
    }

    size_t so = (size_t)r * E_DIM + h * HD_DIM + c4;
    ushort4 ov;
    ov.x = f2bf(acc.x); ov.y = f2bf(acc.y); ov.z = f2bf(acc.z); ov.w = f2bf(acc.w);
    *(ushort4*)(sampb + so) = ov;
}

// ---------------------------------------------------------------------------
// x = LayerNorm(x + y); also writes xb = bf16(x), and qb = bf16(x+pos) if WQ
// ---------------------------------------------------------------------------
template<bool WQ>
__global__ __launch_bounds__(256)
void add_ln_kernel(float* __restrict__ x, const float* __restrict__ y,
                   const float* __restrict__ g, const float* __restrict__ bta,
                   ushort_t* __restrict__ xb, ushort_t* __restrict__ qb,
                   const ushort_t* __restrict__ posb)
{
    int r = blockIdx.x;
    int t = threadIdx.x;
    size_t o = (size_t)r * E_DIM + t;
    float v = x[o] + y[o];
    float s1 = v, s2 = v * v;
    #pragma unroll
    for (int ofs = 32; ofs >= 1; ofs >>= 1) {
        s1 += __shfl_xor(s1, ofs, 64);
        s2 += __shfl_xor(s2, ofs, 64);
    }
    __shared__ float r1[4], r2[4];
    int w = t >> 6;
    if ((t & 63) == 0) { r1[w] = s1; r2[w] = s2; }
    __syncthreads();
    float S1 = r1[0] + r1[1] + r1[2] + r1[3];
    float S2 = r2[0] + r2[1] + r2[2] + r2[3];
    float mean = S1 * (1.f / E_DIM);
    float var  = S2 * (1.f / E_DIM) - mean * mean;
    float out = (v - mean) * rsqrtf(var + 1e-5f) * g[t] + bta[t];
    x[o]  = out;
    xb[o] = f2bf(out);
    if (WQ) qb[o] = f2bf(out + bf2f(posb[o]));
}

// ---------------------------------------------------------------------------
extern "C" void kernel_launch(void* const* d_in, const int* in_sizes, int n_in,
                              void* d_out, int out_size, void* d_ws, size_t ws_size,
                              hipStream_t stream)
{
    const float* f0     = (const float*)d_in[0];
    const float* p0     = (const float*)d_in[1];
    const float* f1     = (const float*)d_in[2];
    const float* p1     = (const float*)d_in[3];
    const float* f2     = (const float*)d_in[4];
    const float* p2     = (const float*)d_in[5];
    const float* f3     = (const float*)d_in[6];
    const float* p3     = (const float*)d_in[7];
    const float* lemb   = (const float*)d_in[8];
    const float* W_off  = (const float*)d_in[9];
    const float* b_off  = (const float*)d_in[10];
    const float* W_attn = (const float*)d_in[11];
    const float* b_attn = (const float*)d_in[12];
    const float* W_val  = (const float*)d_in[13];
    const float* b_val  = (const float*)d_in[14];
    const float* W_out  = (const float*)d_in[15];
    const float* b_out  = (const float*)d_in[16];
    const float* ln1_g  = (const float*)d_in[17];
    const float* ln1_b  = (const float*)d_in[18];
    const float* W_ff1  = (const float*)d_in[19];
    const float* b_ff1  = (const float*)d_in[20];
    const float* W_ff2  = (const float*)d_in[21];
    const float* b_ff2  = (const float*)d_in[22];
    const float* ln2_g  = (const float*)d_in[23];
    const float* ln2_b  = (const float*)d_in[24];

    float* x = (float*)d_out;
    char*  w = (char*)d_ws;

    // ws layout (bytes), total 128,335,872 <= known-safe 129.6 MB
    ushort_t* posb  = (ushort_t*)(w + 0);                       // M_PAD*256*2 = 10,813,440
    float*    tmp   = (float*)   (w + 10813440);                // M*256*4     = 21,602,304
    float*    value = (float*)   (w + 32415744);                // M*256*4     = 21,602,304
    char*     region=            (w + 54018048);                // 43,253,760
    ushort_t* offb  = (ushort_t*)(region);                      // M_PAD*384*2 = 16,220,160
    ushort_t* attnb = (ushort_t*)(region + 16220160);           // M_PAD*128*2 =  5,406,720
    ushort_t* sampb = (ushort_t*)(region + 21626880);           // M_PAD*256*2 = 10,813,440
    ushort_t* hidden= (ushort_t*)(region);                      // M_PAD*1024*2= 43,253,760 (aliases off/attn/samp)
    ushort_t* xb    = (ushort_t*)(w + 97271808);                // 10,813,440
    ushort_t* qb    = (ushort_t*)(w + 108085248);               // 10,813,440
    ushort_t* wb    = (ushort_t*)(w + 118898688);               //  9,437,184

    ushort_t* Wv_t = wb;            // [6][256][256]
    ushort_t* Wo_t = wb + 393216;   // [6][384][256]
    ushort_t* Wa_t = wb + 983040;   // [6][128][256]
    ushort_t* Wp_t = wb + 1179648;  // [6][256][256]
    ushort_t* W1_t = wb + 1572864;  // [6][1024][256]
    ushort_t* W2_t = wb + 3145728;  // [6][256][1024]

    dim3 blk(256);

    transpose_cvt_kernel<<<dim3(8, 8, 6),  blk, 0, stream>>>(W_val,  Wv_t, 256, 256);
    transpose_cvt_kernel<<<dim3(12, 8, 6), blk, 0, stream>>>(W_off,  Wo_t, 256, 384);
    transpose_cvt_kernel<<<dim3(4, 8, 6),  blk, 0, stream>>>(W_attn, Wa_t, 256, 128);
    transpose_cvt_kernel<<<dim3(8, 8, 6),  blk, 0, stream>>>(W_out,  Wp_t, 256, 256);
    transpose_cvt_kernel<<<dim3(32, 8, 6), blk, 0, stream>>>(W_ff1,  W1_t, 256, 1024);
    transpose_cvt_kernel<<<dim3(8, 32, 6), blk, 0, stream>>>(W_ff2,  W2_t, 1024, 256);

    assemble_kernel<<<(M_ROWS * E_DIM) / 256, blk, 0, stream>>>(
        f0, p0, f1, p1, f2, p2, f3, p3, lemb, x, posb, xb, qb);

    const int MT = M_PAD / 128;   // 165
    for (int l = 0; l < NLAYERS; ++l) {
        gemm_bf16<2, false><<<dim3(2, MT), blk, 0, stream>>>(
            xb, Wv_t + l * 65536, b_val + l * 256, value, nullptr, M_ROWS, 256, 256);
        gemm_bf16<1, false><<<dim3(3, MT), blk, 0, stream>>>(
            qb, Wo_t + l * 98304, b_off + l * 384, nullptr, offb, M_ROWS, 384, 256);
        gemm_bf16<1, false><<<dim3(1, MT), blk, 0, stream>>>(
            qb, Wa_t + l * 32768, b_attn + l * 128, nullptr, attnb, M_ROWS, 128, 256);
        sample_kernel<<<(M_ROWS * NH_DIM) / 32, blk, 0, stream>>>(value, offb, attnb, sampb);
        gemm_bf16<0, false><<<dim3(2, MT), blk, 0, stream>>>(
            sampb, Wp_t + l * 65536, b_out + l * 256, tmp, nullptr, M_ROWS, 256, 256);
        add_ln_kernel<false><<<M_ROWS, blk, 0, stream>>>(
            x, tmp, ln1_g + l * 256, ln1_b + l * 256, xb, qb, posb);
        gemm_bf16<1, true><<<dim3(8, MT), blk, 0, stream>>>(
            xb, W1_t + l * 262144, b_ff1 + l * 1024, nullptr, hidden, M_ROWS, 1024, 256);
        gemm_bf16<0, false><<<dim3(2, MT), blk, 0, stream>>>(
            hidden, W2_t + l * 262144, b_ff2 + l * 256, tmp, nullptr, M_ROWS, 256, 1024);
        add_ln_kernel<true><<<M_ROWS, blk, 0, stream>>>(
            x, tmp, ln2_g + l * 256, ln2_b + l * 256, xb, qb, posb);
    }
}

// Round 4
// 1705.653 us; speedup vs baseline: 3.1636x; 1.0505x over previous
//
#include <hip/hip_runtime.h>

#define S_TOT   10548
#define M_ROWS  21096
#define M_PAD   21120          // 165*128 = 330*64
#define E_DIM   256
#define NH_DIM  8
#define HD_DIM  32
#define DF_DIM  1024
#define NLAYERS 6

typedef unsigned short ushort_t;
typedef __attribute__((ext_vector_type(8))) short bf16x8;
typedef __attribute__((ext_vector_type(4))) float f32x4;

__device__ inline ushort_t f2bf(float f) {
    unsigned u = __float_as_uint(f);
    u += 0x7FFF + ((u >> 16) & 1);          // RNE
    return (ushort_t)(u >> 16);
}
__device__ inline float bf2f(ushort_t h) {
    return __uint_as_float(((unsigned)h) << 16);
}

// ---------------------------------------------------------------------------
// Input assembly: x fp32, posb bf16, xb = bf16(x), qb = bf16(x+pos)
// ---------------------------------------------------------------------------
__global__ __launch_bounds__(256)
void assemble_kernel(const float* __restrict__ f0, const float* __restrict__ p0,
                     const float* __restrict__ f1, const float* __restrict__ p1,
                     const float* __restrict__ f2, const float* __restrict__ p2,
                     const float* __restrict__ f3, const float* __restrict__ p3,
                     const float* __restrict__ lemb,
                     float* __restrict__ x, ushort_t* __restrict__ posb,
                     ushort_t* __restrict__ xb, ushort_t* __restrict__ qb)
{
    int idx = blockIdx.x * 256 + threadIdx.x;   // over M_ROWS*E
    int e = idx & (E_DIM - 1);
    int r = idx >> 8;
    int b = (r >= S_TOT) ? 1 : 0;
    int s = r - b * S_TOT;
    const float* f; const float* p; int lvl, j, n;
    if (s < 9216)       { lvl = 0; j = s;         n = 9216; f = f0; p = p0; }
    else if (s < 10368) { lvl = 1; j = s - 9216;  n = 1152; f = f1; p = p1; }
    else if (s < 10512) { lvl = 2; j = s - 10368; n = 144;  f = f2; p = p2; }
    else                { lvl = 3; j = s - 10512; n = 36;   f = f3; p = p3; }
    size_t o = (size_t)(b * E_DIM + e) * n + j;
    float xv = f[o];
    float pv = p[o] + lemb[lvl * E_DIM + e];
    x[idx]    = xv;
    posb[idx] = f2bf(pv);
    xb[idx]   = f2bf(xv);
    qb[idx]   = f2bf(xv + pv);
}

// ---------------------------------------------------------------------------
// Weight convert+transpose: src f32 [L,K,N] -> dst bf16 [L(stride), rowOff+N, K]
// ---------------------------------------------------------------------------
__global__ __launch_bounds__(256)
void transpose_cvt_kernel(const float* __restrict__ src, ushort_t* __restrict__ dst,
                          int K, int N, int dstLayerStride, int dstRowOff)
{
    __shared__ float tile[32][33];
    int l  = blockIdx.z;
    int n0 = blockIdx.x * 32, k0 = blockIdx.y * 32;
    int tx = threadIdx.x & 31, ty = threadIdx.x >> 5;
    const float* s = src + (size_t)l * K * N;
    ushort_t* d    = dst + (size_t)l * dstLayerStride + (size_t)dstRowOff * K;
    #pragma unroll
    for (int i = 0; i < 32; i += 8)
        tile[ty + i][tx] = s[(size_t)(k0 + ty + i) * N + n0 + tx];
    __syncthreads();
    #pragma unroll
    for (int i = 0; i < 32; i += 8)
        d[(size_t)(n0 + ty + i) * K + k0 + tx] = f2bf(tile[tx][ty + i]);
}

// ---------------------------------------------------------------------------
// 64x64 bf16 MFMA GEMM, BK=32, 4 waves in 2x2 grid, each 32x32
// (2x2 of 16x16x32 mfma).
// OUT_MODE: 1 = bf16 [M,N]; 2 = bf16 value-permute (B,NH,S,HD);
//           3 = off/attn split: col<384 -> Cb[M,384], else Cb2[M,128]
// ---------------------------------------------------------------------------
template<int OUT_MODE>
__global__ __launch_bounds__(256)
void gemm64(const ushort_t* __restrict__ A, const ushort_t* __restrict__ Bt,
            const float* __restrict__ bias1, const float* __restrict__ bias2,
            ushort_t* __restrict__ Cb, ushort_t* __restrict__ Cb2,
            int M, int N, int K)
{
    __shared__ short As[64 * 40];
    __shared__ short Bs[64 * 40];
    int t    = threadIdx.x;
    int row0 = blockIdx.y * 64;
    int n0   = blockIdx.x * 64;
    int lane = t & 63;
    int w    = t >> 6;
    int wm   = (w >> 1) * 32;       // wave row offset within tile
    int wn   = (w & 1) * 32;        // wave col offset within tile
    const int quad = lane >> 4, lrow = lane & 15;

    f32x4 acc[2][2];
    #pragma unroll
    for (int i = 0; i < 2; ++i)
        #pragma unroll
        for (int j = 0; j < 2; ++j)
            acc[i][j] = (f32x4){0.f, 0.f, 0.f, 0.f};

    int sr = t >> 2, sk = (t & 3) * 8;

    for (int k0 = 0; k0 < K; k0 += 32) {
        bf16x8 a0 = *(const bf16x8*)(A  + (size_t)(row0 + sr) * K + k0 + sk);
        bf16x8 b0 = *(const bf16x8*)(Bt + (size_t)(n0 + sr)   * K + k0 + sk);
        __syncthreads();
        *(bf16x8*)&As[sr * 40 + sk] = a0;
        *(bf16x8*)&Bs[sr * 40 + sk] = b0;
        __syncthreads();

        bf16x8 af[2], bfr[2];
        #pragma unroll
        for (int i = 0; i < 2; ++i)
            af[i] = *(const bf16x8*)&As[(wm + i * 16 + lrow) * 40 + quad * 8];
        #pragma unroll
        for (int j = 0; j < 2; ++j)
            bfr[j] = *(const bf16x8*)&Bs[(wn + j * 16 + lrow) * 40 + quad * 8];
        #pragma unroll
        for (int i = 0; i < 2; ++i)
            #pragma unroll
            for (int j = 0; j < 2; ++j)
                acc[i][j] = __builtin_amdgcn_mfma_f32_16x16x32_bf16(af[i], bfr[j], acc[i][j], 0, 0, 0);
    }

    #pragma unroll
    for (int j = 0; j < 2; ++j) {
        int col = n0 + wn + j * 16 + lrow;
        float bia = (OUT_MODE == 3)
                  ? ((col < 384) ? bias1[col] : bias2[col - 384])
                  : bias1[col];
        #pragma unroll
        for (int i = 0; i < 2; ++i) {
            #pragma unroll
            for (int rg = 0; rg < 4; ++rg) {
                int row = row0 + wm + i * 16 + quad * 4 + rg;
                if (row < M) {
                    float v = acc[i][j][rg] + bia;
                    if (OUT_MODE == 1) {
                        Cb[(size_t)row * N + col] = f2bf(v);
                    } else if (OUT_MODE == 2) {
                        int b = (row >= S_TOT) ? 1 : 0;
                        int s = row - b * S_TOT;
                        int hh = col >> 5, hd = col & 31;
                        Cb[(((size_t)(b * NH_DIM + hh)) * S_TOT + s) * HD_DIM + hd] = f2bf(v);
                    } else {
                        if (col < 384) Cb [(size_t)row * 384 + col]       = f2bf(v);
                        else           Cb2[(size_t)row * 128 + col - 384] = f2bf(v);
                    }
                }
            }
        }
    }
}

// ---------------------------------------------------------------------------
// 128x128 bf16 MFMA GEMM (for ff1), bf16 out + relu
// ---------------------------------------------------------------------------
__global__ __launch_bounds__(256)
void gemm128_relu(const ushort_t* __restrict__ A, const ushort_t* __restrict__ Bt,
                  const float* __restrict__ bias, ushort_t* __restrict__ Cb,
                  int M, int N, int K)
{
    __shared__ short As[128 * 40];
    __shared__ short Bs[128 * 40];
    int t    = threadIdx.x;
    int row0 = blockIdx.y * 128;
    int n0   = blockIdx.x * 128;
    int lane = t & 63;
    int w    = t >> 6;
    int wm   = (w >> 1) * 64, wn = (w & 1) * 64;
    const int quad = lane >> 4, lrow = lane & 15;

    f32x4 acc[4][4];
    #pragma unroll
    for (int i = 0; i < 4; ++i)
        #pragma unroll
        for (int j = 0; j < 4; ++j)
            acc[i][j] = (f32x4){0.f, 0.f, 0.f, 0.f};

    int sr = t >> 2, sk = (t & 3) * 8;

    for (int k0 = 0; k0 < K; k0 += 32) {
        bf16x8 a0 = *(const bf16x8*)(A  + (size_t)(row0 + sr)      * K + k0 + sk);
        bf16x8 a1 = *(const bf16x8*)(A  + (size_t)(row0 + sr + 64) * K + k0 + sk);
        bf16x8 b0 = *(const bf16x8*)(Bt + (size_t)(n0 + sr)        * K + k0 + sk);
        bf16x8 b1 = *(const bf16x8*)(Bt + (size_t)(n0 + sr + 64)   * K + k0 + sk);
        __syncthreads();
        *(bf16x8*)&As[sr * 40 + sk]        = a0;
        *(bf16x8*)&As[(sr + 64) * 40 + sk] = a1;
        *(bf16x8*)&Bs[sr * 40 + sk]        = b0;
        *(bf16x8*)&Bs[(sr + 64) * 40 + sk] = b1;
        __syncthreads();

        bf16x8 af[4], bfr[4];
        #pragma unroll
        for (int i = 0; i < 4; ++i)
            af[i] = *(const bf16x8*)&As[(wm + i * 16 + lrow) * 40 + quad * 8];
        #pragma unroll
        for (int j = 0; j < 4; ++j)
            bfr[j] = *(const bf16x8*)&Bs[(wn + j * 16 + lrow) * 40 + quad * 8];
        #pragma unroll
        for (int i = 0; i < 4; ++i)
            #pragma unroll
            for (int j = 0; j < 4; ++j)
                acc[i][j] = __builtin_amdgcn_mfma_f32_16x16x32_bf16(af[i], bfr[j], acc[i][j], 0, 0, 0);
    }

    #pragma unroll
    for (int j = 0; j < 4; ++j) {
        int col = n0 + wn + j * 16 + lrow;
        float bia = bias[col];
        #pragma unroll
        for (int i = 0; i < 4; ++i) {
            #pragma unroll
            for (int rg = 0; rg < 4; ++rg) {
                int row = row0 + wm + i * 16 + quad * 4 + rg;
                if (row < M)
                    Cb[(size_t)row * N + col] = f2bf(fmaxf(acc[i][j][rg] + bia, 0.f));
            }
        }
    }
}

// ---------------------------------------------------------------------------
// Fused deformable sampling.
// Block = 256 threads = 32 groups of 8 lanes; group = (b,s,h).
// Phase 1: each thread builds 2 point-records (softmax weight folded in,
//          border-masked axis weights, clamped base index) into skewed LDS.
// Phase 2: each lane owns 4 channels; 8 bf16x4 gathers per point.
// valueb has 512KB guard bands: invalid corners read finite garbage * 0.
// ---------------------------------------------------------------------------
__global__ __launch_bounds__(256)
void sample_kernel(const ushort_t* __restrict__ valueb,
                   const ushort_t* __restrict__ offb,
                   const ushort_t* __restrict__ attnb,
                   ushort_t* __restrict__ sampb)
{
    // group stride 132 floats: bank start (4*gl + 8*p) % 32 -> conflict-free broadcast
    __shared__ float rec[32 * 132];

    const int LD_[4] = {4, 2, 1, 1};
    const int LH_[4] = {48, 24, 12, 6};
    const int LW_[4] = {48, 24, 12, 6};
    const int LS0_[4] = {0, 9216, 10368, 10512};

    int t  = threadIdx.x;
    int gl = t >> 3;                       // local group 0..31
    int G  = blockIdx.x * 32 + gl;        // global group over M*NH
    int h  = G & 7;
    int r  = G >> 3;
    int b  = (r >= S_TOT) ? 1 : 0;
    int s  = r - b * S_TOT;

    float rx, ry, rz;
    {
        int j;
        if (s < 9216)       { j = s;         int qx = j % 48; int q2 = j / 48; int qy = q2 % 48; int qz = q2 / 48;
                              rx = (qx + 0.5f) * (1.f/48); ry = (qy + 0.5f) * (1.f/48); rz = (qz + 0.5f) * (1.f/4); }
        else if (s < 10368) { j = s - 9216;  int qx = j % 24; int q2 = j / 24; int qy = q2 % 24; int qz = q2 / 24;
                              rx = (qx + 0.5f) * (1.f/24); ry = (qy + 0.5f) * (1.f/24); rz = (qz + 0.5f) * (1.f/2); }
        else if (s < 10512) { j = s - 10368; int qx = j % 12; int qy = j / 12;
                              rx = (qx + 0.5f) * (1.f/12); ry = (qy + 0.5f) * (1.f/12); rz = 0.5f; }
        else                { j = s - 10512; int qx = j % 6;  int qy = j / 6;
                              rx = (qx + 0.5f) * (1.f/6);  ry = (qy + 0.5f) * (1.f/6);  rz = 0.5f; }
    }

    // ---- phase 1: 2 points per thread ----
    int p0 = (t & 7) * 2;
    float l0 = bf2f(attnb[(size_t)r * 128 + h * 16 + p0]);
    float l1 = bf2f(attnb[(size_t)r * 128 + h * 16 + p0 + 1]);
    float mx = fmaxf(l0, l1);
    mx = fmaxf(mx, __shfl_xor(mx, 1));
    mx = fmaxf(mx, __shfl_xor(mx, 2));
    mx = fmaxf(mx, __shfl_xor(mx, 4));
    float e0 = __expf(l0 - mx), e1 = __expf(l1 - mx);
    float sm = e0 + e1;
    sm += __shfl_xor(sm, 1);
    sm += __shfl_xor(sm, 2);
    sm += __shfl_xor(sm, 4);
    float inv = 1.f / sm;

    #pragma unroll
    for (int pp = 0; pp < 2; ++pp) {
        int p = p0 + pp;
        float aw = (pp ? e1 : e0) * inv;
        int lvl = p >> 2;
        const int Dl = LD_[lvl], Hl = LH_[lvl], Wl = LW_[lvl];
        size_t base3 = (size_t)r * 384 + h * 48 + p * 3;
        float cx = rx * Wl + bf2f(offb[base3 + 0]) - 0.5f;
        float cy = ry * Hl + bf2f(offb[base3 + 1]) - 0.5f;
        float cz = rz * Dl + bf2f(offb[base3 + 2]) - 0.5f;
        float xf = floorf(cx), yf = floorf(cy), zf = floorf(cz);
        float fx = cx - xf, fy = cy - yf, fz = cz - zf;
        int x0 = (int)xf, y0 = (int)yf, z0 = (int)zf;
        float wx0 = ((unsigned)x0       < (unsigned)Wl) ? 1.f - fx : 0.f;
        float wx1 = ((unsigned)(x0 + 1) < (unsigned)Wl) ? fx       : 0.f;
        float wy0 = ((unsigned)y0       < (unsigned)Hl) ? 1.f - fy : 0.f;
        float wy1 = ((unsigned)(y0 + 1) < (unsigned)Hl) ? fy       : 0.f;
        float wz0 = ((unsigned)z0       < (unsigned)Dl) ? 1.f - fz : 0.f;
        float wz1 = ((unsigned)(z0 + 1) < (unsigned)Dl) ? fz       : 0.f;
        int xc = min(max(x0, -1), Wl - 1);
        int yc = min(max(y0, -1), Hl - 1);
        int zc = min(max(z0, -1), Dl - 1);
        int idx = LS0_[lvl] + (zc * Hl + yc) * Wl + xc;
        float* rp = &rec[gl * 132 + p * 8];
        *(f32x4*)rp       = (f32x4){wx0, wx1, wy0, wy1};
        *(f32x4*)(rp + 4) = (f32x4){wz0 * aw, wz1 * aw, __int_as_float(idx), 0.f};
    }
    __syncthreads();

    // ---- phase 2: gathers ----
    int c4 = (t & 7) * 4;
    const ushort_t* vb = valueb + ((size_t)(b * NH_DIM + h) * S_TOT) * HD_DIM + c4;
    f32x4 acc = (f32x4){0.f, 0.f, 0.f, 0.f};

    #pragma unroll
    for (int p = 0; p < 16; ++p) {
        const int lvl = p >> 2;
        const int SW = LW_[lvl] * HD_DIM;               // row stride in elems
        const int SZ = LH_[lvl] * LW_[lvl] * HD_DIM;    // slab stride
        const float* rp = &rec[gl * 132 + p * 8];
        f32x4 wv = *(const f32x4*)rp;
        f32x4 w2 = *(const f32x4*)(rp + 4);
        int idx = __float_as_int(w2.z);
        const ushort_t* cb = vb + (long long)idx * HD_DIM;
        float wzy00 = wv.z * w2.x, wzy10 = wv.w * w2.x;
        float wzy01 = wv.z * w2.y, wzy11 = wv.w * w2.y;
        float wgt[8] = { wzy00 * wv.x, wzy00 * wv.y, wzy10 * wv.x, wzy10 * wv.y,
                         wzy01 * wv.x, wzy01 * wv.y, wzy11 * wv.x, wzy11 * wv.y };
        const int co[8] = {0, HD_DIM, SW, SW + HD_DIM, SZ, SZ + HD_DIM, SZ + SW, SZ + SW + HD_DIM};
        #pragma unroll
        for (int c = 0; c < 8; ++c) {
            ushort4 u = *(const ushort4*)(cb + co[c]);
            acc.x += wgt[c] * bf2f(u.x);
            acc.y += wgt[c] * bf2f(u.y);
            acc.z += wgt[c] * bf2f(u.z);
            acc.w += wgt[c] * bf2f(u.w);
        }
    }

    ushort4 ov;
    ov.x = f2bf(acc.x); ov.y = f2bf(acc.y); ov.z = f2bf(acc.z); ov.w = f2bf(acc.w);
    *(ushort4*)(sampb + (size_t)r * E_DIM + h * HD_DIM + c4) = ov;
}

// ---------------------------------------------------------------------------
// x = LayerNorm(x + y); writes xb = bf16(x), and qb = bf16(x+pos) if WQ
// ---------------------------------------------------------------------------
template<bool WQ>
__global__ __launch_bounds__(256)
void add_ln_kernel(float* __restrict__ x, const ushort_t* __restrict__ y,
                   const float* __restrict__ g, const float* __restrict__ bta,
                   ushort_t* __restrict__ xb, ushort_t* __restrict__ qb,
                   const ushort_t* __restrict__ posb)
{
    int r = blockIdx.x;
    int t = threadIdx.x;
    size_t o = (size_t)r * E_DIM + t;
    float v = x[o] + bf2f(y[o]);
    float s1 = v, s2 = v * v;
    #pragma unroll
    for (int ofs = 32; ofs >= 1; ofs >>= 1) {
        s1 += __shfl_xor(s1, ofs, 64);
        s2 += __shfl_xor(s2, ofs, 64);
    }
    __shared__ float r1[4], r2[4];
    int w = t >> 6;
    if ((t & 63) == 0) { r1[w] = s1; r2[w] = s2; }
    __syncthreads();
    float S1 = r1[0] + r1[1] + r1[2] + r1[3];
    float S2 = r2[0] + r2[1] + r2[2] + r2[3];
    float mean = S1 * (1.f / E_DIM);
    float var  = S2 * (1.f / E_DIM) - mean * mean;
    float out = (v - mean) * rsqrtf(var + 1e-5f) * g[t] + bta[t];
    x[o]  = out;
    xb[o] = f2bf(out);
    if (WQ) qb[o] = f2bf(out + bf2f(posb[o]));
}

// ---------------------------------------------------------------------------
extern "C" void kernel_launch(void* const* d_in, const int* in_sizes, int n_in,
                              void* d_out, int out_size, void* d_ws, size_t ws_size,
                              hipStream_t stream)
{
    const float* f0     = (const float*)d_in[0];
    const float* p0     = (const float*)d_in[1];
    const float* f1     = (const float*)d_in[2];
    const float* p1     = (const float*)d_in[3];
    const float* f2     = (const float*)d_in[4];
    const float* p2     = (const float*)d_in[5];
    const float* f3     = (const float*)d_in[6];
    const float* p3     = (const float*)d_in[7];
    const float* lemb   = (const float*)d_in[8];
    const float* W_off  = (const float*)d_in[9];
    const float* b_off  = (const float*)d_in[10];
    const float* W_attn = (const float*)d_in[11];
    const float* b_attn = (const float*)d_in[12];
    const float* W_val  = (const float*)d_in[13];
    const float* b_val  = (const float*)d_in[14];
    const float* W_out  = (const float*)d_in[15];
    const float* b_out  = (const float*)d_in[16];
    const float* ln1_g  = (const float*)d_in[17];
    const float* ln1_b  = (const float*)d_in[18];
    const float* W_ff1  = (const float*)d_in[19];
    const float* b_ff1  = (const float*)d_in[20];
    const float* W_ff2  = (const float*)d_in[21];
    const float* b_ff2  = (const float*)d_in[22];
    const float* ln2_g  = (const float*)d_in[23];
    const float* ln2_b  = (const float*)d_in[24];

    float* x = (float*)d_out;
    char*  w = (char*)d_ws;

    // ws layout (bytes), total 107,794,432
    ushort_t* posb   = (ushort_t*)(w + 0);                  // 10,813,440
    ushort_t* tmpb   = (ushort_t*)(w + 10813440);           // 10,813,440
    ushort_t* valueb = (ushort_t*)(w + 21626880 + 524288);  // guard|10,801,152|guard
    char*     region =            (w + 33476608);           // 43,253,760 (hidden)
    ushort_t* offb   = (ushort_t*)(region);                 // 16,220,160
    ushort_t* attnb  = (ushort_t*)(region + 16220160);      //  5,406,720
    ushort_t* sampb  = (ushort_t*)(region + 21626880);      // 10,813,440
    ushort_t* hidden = (ushort_t*)(region);                 // 43,253,760
    ushort_t* xb     = (ushort_t*)(w + 76730368);           // 10,813,440
    ushort_t* qb     = (ushort_t*)(w + 87543808);           // 10,813,440
    ushort_t* wb     = (ushort_t*)(w + 98357248);           //  9,437,184

    ushort_t* Wv_t  = wb;             // [6][256][256]
    ushort_t* Woa_t = wb + 393216;    // [6][512][256]  (off rows 0..383, attn rows 384..511)
    ushort_t* Wp_t  = wb + 1179648;   // [6][256][256]
    ushort_t* W1_t  = wb + 1572864;   // [6][1024][256]
    ushort_t* W2_t  = wb + 3145728;   // [6][256][1024]

    dim3 blk(256);

    transpose_cvt_kernel<<<dim3(8, 8, 6),  blk, 0, stream>>>(W_val,  Wv_t,  256, 256,  65536, 0);
    transpose_cvt_kernel<<<dim3(12, 8, 6), blk, 0, stream>>>(W_off,  Woa_t, 256, 384, 131072, 0);
    transpose_cvt_kernel<<<dim3(4, 8, 6),  blk, 0, stream>>>(W_attn, Woa_t, 256, 128, 131072, 384);
    transpose_cvt_kernel<<<dim3(8, 8, 6),  blk, 0, stream>>>(W_out,  Wp_t,  256, 256,  65536, 0);
    transpose_cvt_kernel<<<dim3(32, 8, 6), blk, 0, stream>>>(W_ff1,  W1_t,  256, 1024, 262144, 0);
    transpose_cvt_kernel<<<dim3(8, 32, 6), blk, 0, stream>>>(W_ff2,  W2_t,  1024, 256, 262144, 0);

    assemble_kernel<<<(M_ROWS * E_DIM) / 256, blk, 0, stream>>>(
        f0, p0, f1, p1, f2, p2, f3, p3, lemb, x, posb, xb, qb);

    const int MT64 = M_PAD / 64;    // 330
    const int MT128 = M_PAD / 128;  // 165
    for (int l = 0; l < NLAYERS; ++l) {
        gemm64<2><<<dim3(4, MT64), blk, 0, stream>>>(
            xb, Wv_t + l * 65536, b_val + l * 256, nullptr, valueb, nullptr, M_ROWS, 256, 256);
        gemm64<3><<<dim3(8, MT64), blk, 0, stream>>>(
            qb, Woa_t + l * 131072, b_off + l * 384, b_attn + l * 128, offb, attnb, M_ROWS, 512, 256);
        sample_kernel<<<(M_ROWS * NH_DIM) / 32, blk, 0, stream>>>(valueb, offb, attnb, sampb);
        gemm64<1><<<dim3(4, MT64), blk, 0, stream>>>(
            sampb, Wp_t + l * 65536, b_out + l * 256, nullptr, tmpb, nullptr, M_ROWS, 256, 256);
        add_ln_kernel<false><<<M_ROWS, blk, 0, stream>>>(
            x, tmpb, ln1_g + l * 256, ln1_b + l * 256, xb, qb, posb);
        gemm128_relu<<<dim3(8, MT128), blk, 0, stream>>>(
            xb, W1_t + l * 262144, b_ff1 + l * 1024, hidden, M_ROWS, 1024, 256);
        gemm64<1><<<dim3(4, MT64), blk, 0, stream>>>(
            hidden, W2_t + l * 262144, b_ff2 + l * 256, nullptr, tmpb, nullptr, M_ROWS, 256, 1024);
        add_ln_kernel<true><<<M_ROWS, blk, 0, stream>>>(
            x, tmpb, ln2_g + l * 256, ln2_b + l * 256, xb, qb, posb);
    }
}